// Round 15
// baseline (289.215 us; speedup 1.0000x reference)
//
#include <hip/hip_runtime.h>
#include <cstdint>
#include <cstddef>

// Problem constants (fixed by the reference)
#define NN    4096      // nodes
#define E0C   32768     // raw edges
#define ETC   (E0C+NN)  // edges + self loops = 36864
#define HC1   8         // heads layer1
#define CC    512       // channels per head (both layers)
#define F_IN  128
#define NEG_SLOPE_F 0.2f
#define ELLW  64        // ELL width; max in-degree ~Poisson(9) << 64

typedef __bf16 bf16_t;
typedef __bf16 bf16x8 __attribute__((ext_vector_type(8)));
typedef __bf16 bf16x4 __attribute__((ext_vector_type(4)));
typedef __bf16 bf16x2 __attribute__((ext_vector_type(2)));
typedef float  f32x4  __attribute__((ext_vector_type(4)));

// ---------- fused prep: region-dispatched ----------
__device__ __forceinline__ void tcast_body(const float* __restrict__ W, bf16_t* __restrict__ Wt,
                                           int K, int N, int bx, int by)
{
    __shared__ float t[32][33];
    int bn = bx * 32, bk = by * 32;
    int tx = threadIdx.x & 31, ty = threadIdx.x >> 5;
    #pragma unroll
    for (int i = 0; i < 32; i += 8)
        t[ty + i][tx] = W[(size_t)(bk + ty + i) * N + bn + tx];
    __syncthreads();
    #pragma unroll
    for (int i = 0; i < 32; i += 8)
        Wt[(size_t)(bn + ty + i) * K + bk + tx] = (bf16_t)t[tx][ty + i];
}

__global__ __launch_bounds__(256) void prep_k(const float* __restrict__ x,
    const float* __restrict__ W1, const float* __restrict__ W2,
    const float* __restrict__ fc1w, const float* __restrict__ a_src1,
    const float* __restrict__ a_dst1, const int* __restrict__ ei,
    bf16_t* __restrict__ x_bf, bf16_t* __restrict__ Wt1, bf16_t* __restrict__ Wt2,
    bf16_t* __restrict__ fc1wt, bf16_t* __restrict__ w1sT,
    int* __restrict__ srcELL, int* __restrict__ indeg)
{
    const int b = blockIdx.x;
    if (b < 512) {
        int i = (b * 256 + threadIdx.x) * 4;
        float4 v = *(const float4*)&x[i];
        bf16x4 o;
        o[0] = (bf16_t)v.x; o[1] = (bf16_t)v.y; o[2] = (bf16_t)v.z; o[3] = (bf16_t)v.w;
        *(bf16x4*)&x_bf[i] = o;
    } else if (b < 1024) {
        int bl = b - 512;
        tcast_body(W1, Wt1, F_IN, 4096, bl % 128, bl / 128);
    } else if (b < 3072) {
        int bl = b - 1024;
        tcast_body(W2, Wt2, 4096, 512, bl % 16, bl / 16);
    } else if (b < 5120) {
        int bl = b - 3072;
        tcast_body(fc1w, fc1wt, 4096, 512, bl % 16, bl / 16);
    } else if (b < 5152) {
        int bl = b - 5120;                     // 0..31
        int wave = threadIdx.x >> 6, lane = threadIdx.x & 63;
        int k = bl * 4 + wave;                 // 0..127
        int hd = lane >> 3;
        int co = (lane & 7) * 64;
        const float* wrow = W1 + (size_t)k * (HC1 * CC) + hd * CC + co;
        const float* vs = a_src1 + hd * CC + co;
        const float* vd = a_dst1 + hd * CC + co;
        float s = 0.f, d = 0.f;
        #pragma unroll 4
        for (int t = 0; t < 64; ++t) {
            float w = wrow[t];
            s += w * vs[t];
            d += w * vd[t];
        }
        #pragma unroll
        for (int off = 1; off < 8; off <<= 1) {
            s += __shfl_xor(s, off);
            d += __shfl_xor(d, off);
        }
        if ((lane & 7) == 0) {
            w1sT[hd * F_IN + k]       = (bf16_t)s;
            w1sT[(hd + 8) * F_IN + k] = (bf16_t)d;
        }
    } else {
        int e = (b - 5152) * 256 + threadIdx.x;
        if (e < ETC) {
            int s, d;
            if (e < E0C) { s = ei[e]; d = ei[E0C + e]; }
            else         { s = e - E0C; d = s; }
            int pos = atomicAdd(&indeg[d], 1);
            if (pos < ELLW) srcELL[d * ELLW + pos] = s;
        }
    }
}

// ---------- alpha1 via MFMA: [NN x 16] = x_bf[NN x 128] @ w1sT[16 x 128]^T ----------
__global__ __launch_bounds__(256) void alpha1_k(const bf16_t* __restrict__ x_bf,
                                                const bf16_t* __restrict__ w1sT,
                                                float* __restrict__ as1, float* __restrict__ ad1)
{
    const int wave = threadIdx.x >> 6, lane = threadIdx.x & 63;
    const int bm = blockIdx.x * 64 + wave * 16;
    const int lm = lane & 15, quad = lane >> 4;
    f32x4 acc = {};
    #pragma unroll
    for (int k0 = 0; k0 < F_IN; k0 += 32) {
        bf16x8 af = *(const bf16x8*)&x_bf[(size_t)(bm + lm) * F_IN + k0 + quad * 8];
        bf16x8 bf = *(const bf16x8*)&w1sT[lm * F_IN + k0 + quad * 8];
        acc = __builtin_amdgcn_mfma_f32_16x16x32_bf16(af, bf, acc, 0, 0, 0);
    }
    #pragma unroll
    for (int r = 0; r < 4; ++r) {
        int n = bm + quad * 4 + r;
        if (lm < 8) as1[n * HC1 + lm] = acc[r];
        else        ad1[n * HC1 + (lm - 8)] = acc[r];
    }
}

// ---------- layer-1 x-space aggregation: wave per node, all 8 heads ----------
__global__ __launch_bounds__(256) void aggx_k(const bf16_t* __restrict__ x_bf,
    const float* __restrict__ as1, const float* __restrict__ ad1,
    const int* __restrict__ indeg, const int* __restrict__ srcELL,
    bf16_t* __restrict__ xagg)
{
    const int wave = threadIdx.x >> 6, lane = threadIdx.x & 63;
    const int n = blockIdx.x * 4 + wave;
    const int c = lane * 2;
    const int deg = min(indeg[n], ELLW);

    int vsrc = 0;
    float vp[HC1] = {};
    if (lane < deg) {
        vsrc = srcELL[n * ELLW + lane];
        #pragma unroll
        for (int hd = 0; hd < HC1; ++hd) {
            float v = as1[vsrc * HC1 + hd] + ad1[n * HC1 + hd];
            v = (v > 0.f) ? v : NEG_SLOPE_F * v;
            vp[hd] = __expf(v);
        }
    }
    #pragma unroll
    for (int hd = 0; hd < HC1; ++hd) {
        float dsum = vp[hd];
        #pragma unroll
        for (int off = 1; off < 64; off <<= 1)
            dsum += __shfl_xor(dsum, off);
        vp[hd] *= 1.f / dsum;
    }

    float acc[HC1][2] = {};
    int ii = 0;
    for (; ii + 2 <= deg; ii += 2) {
        int s0 = __shfl(vsrc, ii), s1 = __shfl(vsrc, ii + 1);
        bf16x2 r0 = *(const bf16x2*)&x_bf[(size_t)s0 * F_IN + c];
        bf16x2 r1 = *(const bf16x2*)&x_bf[(size_t)s1 * F_IN + c];
        float f00 = (float)r0[0], f01 = (float)r0[1];
        float f10 = (float)r1[0], f11 = (float)r1[1];
        #pragma unroll
        for (int hd = 0; hd < HC1; ++hd) {
            float a0 = __shfl(vp[hd], ii);
            float a1 = __shfl(vp[hd], ii + 1);
            acc[hd][0] += a0 * f00 + a1 * f10;
            acc[hd][1] += a0 * f01 + a1 * f11;
        }
    }
    for (; ii < deg; ++ii) {
        int s = __shfl(vsrc, ii);
        bf16x2 rv = *(const bf16x2*)&x_bf[(size_t)s * F_IN + c];
        float r0 = (float)rv[0], r1 = (float)rv[1];
        #pragma unroll
        for (int hd = 0; hd < HC1; ++hd) {
            float al = __shfl(vp[hd], ii);
            acc[hd][0] += al * r0;
            acc[hd][1] += al * r1;
        }
    }
    #pragma unroll
    for (int hd = 0; hd < HC1; ++hd) {
        bf16x2 o;
        o[0] = (bf16_t)acc[hd][0];
        o[1] = (bf16_t)acc[hd][1];
        *(bf16x2*)&xagg[((size_t)n * HC1 + hd) * F_IN + c] = o;
    }
}

// ---------- per-head batched GEMM: out1[:, hd*512:+512] = relu(xagg[:,hd,:] @ W1h + b1) ----------
__global__ __launch_bounds__(256, 2) void gemmh_k(const bf16_t* __restrict__ xagg,
                                                  const bf16_t* __restrict__ Wt1,
                                                  const float* __restrict__ b1,
                                                  bf16_t* __restrict__ out1)
{
    __shared__ bf16_t As[128 * 32];
    __shared__ bf16_t Bs[128 * 32];
    const int tid = threadIdx.x;
    const int bm = blockIdx.x * 128, bn = blockIdx.y * 128;
    const int hd = blockIdx.z;

    const int wave = tid >> 6, lane = tid & 63;
    const int wm = wave >> 1, wn = wave & 1;
    const int lm = lane & 15, quad = lane >> 4;

    const int sr = tid >> 2;
    const int kg = tid & 3;
    const int swz = ((kg ^ (sr & 3)) * 8);

    const bf16_t* Aptr = xagg + ((size_t)(bm + sr) * HC1 + hd) * F_IN + kg * 8;
    const bf16_t* Bptr = Wt1 + (size_t)(hd * CC + bn + sr) * F_IN + kg * 8;
    const size_t raskip = (size_t)64 * HC1 * F_IN;
    const size_t rbskip = (size_t)64 * F_IN;

    bf16x8 ra0 = *(const bf16x8*)(Aptr);
    bf16x8 ra1 = *(const bf16x8*)(Aptr + raskip);
    bf16x8 rb0 = *(const bf16x8*)(Bptr);
    bf16x8 rb1 = *(const bf16x8*)(Bptr + rbskip);

    f32x4 acc[4][4] = {};

    for (int k0 = 0; k0 < F_IN; k0 += 32) {
        __syncthreads();
        *(bf16x8*)&As[sr * 32 + swz]        = ra0;
        *(bf16x8*)&As[(sr + 64) * 32 + swz] = ra1;
        *(bf16x8*)&Bs[sr * 32 + swz]        = rb0;
        *(bf16x8*)&Bs[(sr + 64) * 32 + swz] = rb1;
        __syncthreads();
        if (k0 + 32 < F_IN) {
            Aptr += 32; Bptr += 32;
            ra0 = *(const bf16x8*)(Aptr);
            ra1 = *(const bf16x8*)(Aptr + raskip);
            rb0 = *(const bf16x8*)(Bptr);
            rb1 = *(const bf16x8*)(Bptr + rbskip);
        }
        const int fswz = ((quad ^ (lm & 3)) * 8);
        bf16x8 af[4], bfr[4];
        #pragma unroll
        for (int i = 0; i < 4; ++i) {
            af[i]  = *(const bf16x8*)&As[(wm * 64 + i * 16 + lm) * 32 + fswz];
            bfr[i] = *(const bf16x8*)&Bs[(wn * 64 + i * 16 + lm) * 32 + fswz];
        }
        #pragma unroll
        for (int mt = 0; mt < 4; ++mt)
            #pragma unroll
            for (int nt = 0; nt < 4; ++nt)
                acc[mt][nt] = __builtin_amdgcn_mfma_f32_16x16x32_bf16(af[mt], bfr[nt], acc[mt][nt], 0, 0, 0);
    }

    #pragma unroll
    for (int nt = 0; nt < 4; ++nt) {
        int gc = bn + wn * 64 + nt * 16 + lm;
        float bv = b1[hd * CC + gc];
        #pragma unroll
        for (int mt = 0; mt < 4; ++mt)
            #pragma unroll
            for (int r = 0; r < 4; ++r) {
                int gr = bm + wm * 64 + mt * 16 + quad * 4 + r;
                out1[(size_t)gr * 4096 + hd * CC + gc] = (bf16_t)fmaxf(acc[mt][nt][r] + bv, 0.f);
            }
    }
}

// ---------- gemm2 fused: 128x128 MFMA split-K=4 + ticketed last-block reduce ----------
// Last kz-block per (bm,bn) tile sums the 4 bf16 partials, writes h2 (bf16) and
// accumulates as2/ad2 row-dots (device-scope atomics).
__global__ __launch_bounds__(256, 2) void gemm2f_k(const bf16_t* __restrict__ A,
                                                   const bf16_t* __restrict__ Bt,
                                                   bf16_t* __restrict__ Cpart,
                                                   int* __restrict__ ticket,
                                                   const float* __restrict__ a_s,
                                                   const float* __restrict__ a_d,
                                                   bf16_t* __restrict__ h2out,
                                                   float* __restrict__ as2,
                                                   float* __restrict__ ad2)
{
    const int M = NN, N = CC, K = 4096, Kc = 1024;
    __shared__ bf16_t As[128 * 32];
    __shared__ bf16_t Bs[128 * 32];
    const int tid = threadIdx.x;
    const int bm = blockIdx.x * 128, bn = blockIdx.y * 128;
    const int kz = blockIdx.z;
    const int k_beg = kz * Kc;
    const int k_end = k_beg + Kc;

    const int wave = tid >> 6, lane = tid & 63;
    const int wm = wave >> 1, wn = wave & 1;
    const int lm = lane & 15, quad = lane >> 4;

    const int sr = tid >> 2;
    const int kg = tid & 3;
    const int swz = ((kg ^ (sr & 3)) * 8);

    const bf16_t* Aptr = A + (size_t)(bm + sr) * K + k_beg + kg * 8;
    const bf16_t* Bptr = Bt + (size_t)(bn + sr) * K + k_beg + kg * 8;
    const size_t rowskip = (size_t)64 * K;

    bf16x8 ra0 = *(const bf16x8*)(Aptr);
    bf16x8 ra1 = *(const bf16x8*)(Aptr + rowskip);
    bf16x8 rb0 = *(const bf16x8*)(Bptr);
    bf16x8 rb1 = *(const bf16x8*)(Bptr + rowskip);

    f32x4 acc[4][4] = {};

    for (int k0 = k_beg; k0 < k_end; k0 += 32) {
        __syncthreads();
        *(bf16x8*)&As[sr * 32 + swz]        = ra0;
        *(bf16x8*)&As[(sr + 64) * 32 + swz] = ra1;
        *(bf16x8*)&Bs[sr * 32 + swz]        = rb0;
        *(bf16x8*)&Bs[(sr + 64) * 32 + swz] = rb1;
        __syncthreads();
        if (k0 + 32 < k_end) {
            Aptr += 32; Bptr += 32;
            ra0 = *(const bf16x8*)(Aptr);
            ra1 = *(const bf16x8*)(Aptr + rowskip);
            rb0 = *(const bf16x8*)(Bptr);
            rb1 = *(const bf16x8*)(Bptr + rowskip);
        }
        const int fswz = ((quad ^ (lm & 3)) * 8);
        bf16x8 af[4], bfr[4];
        #pragma unroll
        for (int i = 0; i < 4; ++i) {
            af[i]  = *(const bf16x8*)&As[(wm * 64 + i * 16 + lm) * 32 + fswz];
            bfr[i] = *(const bf16x8*)&Bs[(wn * 64 + i * 16 + lm) * 32 + fswz];
        }
        #pragma unroll
        for (int mt = 0; mt < 4; ++mt)
            #pragma unroll
            for (int nt = 0; nt < 4; ++nt)
                acc[mt][nt] = __builtin_amdgcn_mfma_f32_16x16x32_bf16(af[mt], bfr[nt], acc[mt][nt], 0, 0, 0);
    }

    // write own partial (bf16)
    bf16_t* P = Cpart + (size_t)kz * M * N;
    #pragma unroll
    for (int nt = 0; nt < 4; ++nt) {
        int gc = bn + wn * 64 + nt * 16 + lm;
        #pragma unroll
        for (int mt = 0; mt < 4; ++mt)
            #pragma unroll
            for (int r = 0; r < 4; ++r) {
                int gr = bm + wm * 64 + mt * 16 + quad * 4 + r;
                P[(size_t)gr * N + gc] = (bf16_t)acc[mt][nt][r];
            }
    }

    // ticket: last block of the 4 kz reduces
    __threadfence();
    __syncthreads();
    __shared__ int s_old;
    if (tid == 0) s_old = atomicAdd(&ticket[blockIdx.x * 4 + blockIdx.y], 1);
    __syncthreads();
    if (s_old != 3) return;
    __threadfence();

    #pragma unroll
    for (int mt = 0; mt < 4; ++mt) {
        #pragma unroll
        for (int r = 0; r < 4; ++r) {
            const int gr = bm + wm * 64 + mt * 16 + quad * 4 + r;
            float rs = 0.f, rd = 0.f;
            #pragma unroll
            for (int nt = 0; nt < 4; ++nt) {
                int gc = bn + wn * 64 + nt * 16 + lm;
                float v = 0.f;
                #pragma unroll
                for (int z = 0; z < 4; ++z)
                    v += (float)Cpart[(size_t)z * M * N + (size_t)gr * N + gc];
                h2out[(size_t)gr * N + gc] = (bf16_t)v;
                rs += v * a_s[gc];
                rd += v * a_d[gc];
            }
            #pragma unroll
            for (int off = 1; off < 16; off <<= 1) {
                rs += __shfl_xor(rs, off);
                rd += __shfl_xor(rd, off);
            }
            if (lm == 0) {
                atomicAdd(&as2[gr], rs);
                atomicAdd(&ad2[gr], rd);
            }
        }
    }
}

// ---------- 128x128 MFMA GEMM (NT), XOR-swizzled LDS, split-K, bf16 partials (fc1) ----------
__global__ __launch_bounds__(256, 2) void gemm128s_k(const bf16_t* __restrict__ A,
                                                     const bf16_t* __restrict__ Bt,
                                                     bf16_t* __restrict__ Cpart,
                                                     int M, int N, int K, int Kc)
{
    __shared__ bf16_t As[128 * 32];
    __shared__ bf16_t Bs[128 * 32];
    const int tid = threadIdx.x;
    const int bm = blockIdx.x * 128, bn = blockIdx.y * 128;
    const int kz = blockIdx.z;
    const int k_beg = kz * Kc;
    const int k_end = k_beg + Kc;

    const int wave = tid >> 6, lane = tid & 63;
    const int wm = wave >> 1, wn = wave & 1;
    const int lm = lane & 15, quad = lane >> 4;

    const int sr = tid >> 2;
    const int kg = tid & 3;
    const int swz = ((kg ^ (sr & 3)) * 8);

    const bf16_t* Aptr = A + (size_t)(bm + sr) * K + k_beg + kg * 8;
    const bf16_t* Bptr = Bt + (size_t)(bn + sr) * K + k_beg + kg * 8;
    const size_t rowskip = (size_t)64 * K;

    bf16x8 ra0 = *(const bf16x8*)(Aptr);
    bf16x8 ra1 = *(const bf16x8*)(Aptr + rowskip);
    bf16x8 rb0 = *(const bf16x8*)(Bptr);
    bf16x8 rb1 = *(const bf16x8*)(Bptr + rowskip);

    f32x4 acc[4][4] = {};

    for (int k0 = k_beg; k0 < k_end; k0 += 32) {
        __syncthreads();
        *(bf16x8*)&As[sr * 32 + swz]        = ra0;
        *(bf16x8*)&As[(sr + 64) * 32 + swz] = ra1;
        *(bf16x8*)&Bs[sr * 32 + swz]        = rb0;
        *(bf16x8*)&Bs[(sr + 64) * 32 + swz] = rb1;
        __syncthreads();
        if (k0 + 32 < k_end) {
            Aptr += 32; Bptr += 32;
            ra0 = *(const bf16x8*)(Aptr);
            ra1 = *(const bf16x8*)(Aptr + rowskip);
            rb0 = *(const bf16x8*)(Bptr);
            rb1 = *(const bf16x8*)(Bptr + rowskip);
        }
        const int fswz = ((quad ^ (lm & 3)) * 8);
        bf16x8 af[4], bfr[4];
        #pragma unroll
        for (int i = 0; i < 4; ++i) {
            af[i]  = *(const bf16x8*)&As[(wm * 64 + i * 16 + lm) * 32 + fswz];
            bfr[i] = *(const bf16x8*)&Bs[(wn * 64 + i * 16 + lm) * 32 + fswz];
        }
        #pragma unroll
        for (int mt = 0; mt < 4; ++mt)
            #pragma unroll
            for (int nt = 0; nt < 4; ++nt)
                acc[mt][nt] = __builtin_amdgcn_mfma_f32_16x16x32_bf16(af[mt], bfr[nt], acc[mt][nt], 0, 0, 0);
    }

    bf16_t* P = Cpart + (size_t)kz * M * N;
    #pragma unroll
    for (int nt = 0; nt < 4; ++nt) {
        int gc = bn + wn * 64 + nt * 16 + lm;
        #pragma unroll
        for (int mt = 0; mt < 4; ++mt)
            #pragma unroll
            for (int r = 0; r < 4; ++r) {
                int gr = bm + wm * 64 + mt * 16 + quad * 4 + r;
                P[(size_t)gr * N + gc] = (bf16_t)acc[mt][nt][r];
            }
    }
}

// ---------- fused tail: f1-row = relu(sum_16 bf16 partials + b); fc2; fc3 ----------
__global__ __launch_bounds__(128) void tail_k(const bf16_t* __restrict__ P,
                                              const float* __restrict__ fc1b,
                                              const float* __restrict__ fc2w,
                                              const float* __restrict__ fc2b,
                                              const float* __restrict__ fc3w,
                                              const float* __restrict__ fc3b,
                                              float* __restrict__ out)
{
    __shared__ float sA[512];
    __shared__ float sF2[128];
    const int m = blockIdx.x, t = threadIdx.x;
    const int MN = 512 * 512;
    #pragma unroll
    for (int i = 0; i < 4; ++i) {
        int c = t + i * 128;
        float v = 0.f;
        #pragma unroll
        for (int z = 0; z < 16; ++z)
            v += (float)P[(size_t)z * MN + (size_t)m * 512 + c];
        sA[c] = fmaxf(v + fc1b[c], 0.f);
    }
    __syncthreads();
    float a0 = 0.f, a1 = 0.f, a2 = 0.f, a3 = 0.f;
    #pragma unroll 4
    for (int k = 0; k < 512; k += 4) {
        a0 += sA[k + 0] * fc2w[(k + 0) * 128 + t];
        a1 += sA[k + 1] * fc2w[(k + 1) * 128 + t];
        a2 += sA[k + 2] * fc2w[(k + 2) * 128 + t];
        a3 += sA[k + 3] * fc2w[(k + 3) * 128 + t];
    }
    sF2[t] = fmaxf((a0 + a1) + (a2 + a3) + fc2b[t], 0.f);
    __syncthreads();
    if (t < 10) {
        float o = fc3b[t];
        #pragma unroll 4
        for (int k = 0; k < 128; ++k)
            o += sF2[k] * fc3w[k * 10 + t];
        out[(size_t)m * 10 + t] = o;
    }
}

// ---------- layer-2 aggregation: one WAVE per node, fused edge-softmax, ELL ----------
__global__ __launch_bounds__(256) void aggregate2_k(const bf16_t* __restrict__ hbuf,
    const float* __restrict__ as, const float* __restrict__ ad,
    const int* __restrict__ indeg, const int* __restrict__ srcELL,
    const float* __restrict__ bias, bf16_t* __restrict__ outb)
{
    const int g = blockIdx.x;
    const int wave = threadIdx.x >> 6, lane = threadIdx.x & 63;
    const int n = g * 4 + wave;
    const int c = lane * 8;

    const int deg = min(indeg[n], ELLW);
    const float adn = ad[n];

    int vsrc = 0; float vp = 0.f;
    if (lane < deg) {
        vsrc = srcELL[n * ELLW + lane];
        float v = as[vsrc] + adn;
        v = (v > 0.f) ? v : NEG_SLOPE_F * v;
        vp = __expf(v);
    }
    float denom = vp;
    #pragma unroll
    for (int off = 1; off < 64; off <<= 1)
        denom += __shfl_xor(denom, off);
    vp *= 1.f / denom;

    float acc[8] = {};
    int ii = 0;
    for (; ii + 4 <= deg; ii += 4) {
        int s0 = __shfl(vsrc, ii),     s1 = __shfl(vsrc, ii + 1);
        int s2 = __shfl(vsrc, ii + 2), s3 = __shfl(vsrc, ii + 3);
        float a0 = __shfl(vp, ii),     a1 = __shfl(vp, ii + 1);
        float a2 = __shfl(vp, ii + 2), a3 = __shfl(vp, ii + 3);
        bf16x8 r0 = *(const bf16x8*)&hbuf[(size_t)s0 * CC + c];
        bf16x8 r1 = *(const bf16x8*)&hbuf[(size_t)s1 * CC + c];
        bf16x8 r2 = *(const bf16x8*)&hbuf[(size_t)s2 * CC + c];
        bf16x8 r3 = *(const bf16x8*)&hbuf[(size_t)s3 * CC + c];
        #pragma unroll
        for (int j = 0; j < 8; ++j) {
            acc[j] += a0 * (float)r0[j];
            acc[j] += a1 * (float)r1[j];
            acc[j] += a2 * (float)r2[j];
            acc[j] += a3 * (float)r3[j];
        }
    }
    for (; ii < deg; ++ii) {
        int s = __shfl(vsrc, ii);
        float al = __shfl(vp, ii);
        bf16x8 rv = *(const bf16x8*)&hbuf[(size_t)s * CC + c];
        #pragma unroll
        for (int j = 0; j < 8; ++j)
            acc[j] += al * (float)rv[j];
    }
    size_t ob = (size_t)n * CC;
    bf16x8 o;
    #pragma unroll
    for (int j = 0; j < 8; ++j)
        o[j] = (bf16_t)fmaxf(acc[j] + bias[c + j], 0.f);
    *(bf16x8*)&outb[ob + c] = o;
}

extern "C" void kernel_launch(void* const* d_in, const int* in_sizes, int n_in,
                              void* d_out, int out_size, void* d_ws, size_t ws_size,
                              hipStream_t stream) {
    const float* x      = (const float*)d_in[0];
    const int*   ei     = (const int*)d_in[1];
    // d_in[2] edge_attr: ignored (GATConv has no edge_dim)
    const float* W1     = (const float*)d_in[3];
    const float* a_src1 = (const float*)d_in[4];
    const float* a_dst1 = (const float*)d_in[5];
    const float* b1     = (const float*)d_in[6];
    const float* W2     = (const float*)d_in[7];
    const float* a_src2 = (const float*)d_in[8];
    const float* a_dst2 = (const float*)d_in[9];
    const float* b2     = (const float*)d_in[10];
    const float* fc1w   = (const float*)d_in[11];
    const float* fc1b   = (const float*)d_in[12];
    const float* fc2w   = (const float*)d_in[13];
    const float* fc2b   = (const float*)d_in[14];
    const float* fc3w   = (const float*)d_in[15];
    const float* fc3b   = (const float*)d_in[16];
    float* out = (float*)d_out;

    // ---- workspace carve-up ----
    char* ws = (char*)d_ws;
    size_t o = 0;
    auto take = [&](size_t bytes) -> char* {
        char* p = ws + o;
        o = (o + bytes + 255) & ~(size_t)255;
        return p;
    };
    // zero-initialized block
    int*    indeg  = (int*)take(NN * 4);
    float*  as2    = (float*)take(NN * 4);
    float*  ad2    = (float*)take(NN * 4);
    int*    ticket = (int*)take(128 * 4);
    size_t zero_bytes = o;
    // rest
    int*    srcELL = (int*)take((size_t)NN * ELLW * 4);
    float*  as1    = (float*)take((size_t)NN * HC1 * 4);
    float*  ad1    = (float*)take((size_t)NN * HC1 * 4);
    bf16_t* w1sT   = (bf16_t*)take((size_t)16 * F_IN * 2);
    bf16_t* x_bf   = (bf16_t*)take((size_t)NN * F_IN * 2);
    bf16_t* xagg   = (bf16_t*)take((size_t)NN * HC1 * F_IN * 2);   // [N][H][128]
    bf16_t* Wt1    = (bf16_t*)take((size_t)F_IN * 4096 * 2);       // [4096][128]
    bf16_t* Wt2    = (bf16_t*)take((size_t)4096 * 512 * 2);        // [512][4096]
    bf16_t* fc1wt  = (bf16_t*)take((size_t)4096 * 512 * 2);        // [512][4096]
    bf16_t* out1bf = (bf16_t*)take((size_t)NN * 4096 * 2);         // GAT1 out (bf16)
    bf16_t* h2bf   = (bf16_t*)take((size_t)NN * 512 * 2);          // GEMM2 out (bf16)
    bf16_t* out2bf = (bf16_t*)take((size_t)NN * 512 * 2);          // GAT2 out (bf16)
    bf16_t* part   = (bf16_t*)take((size_t)4 * NN * 512 * 2);      // split-K partials (bf16, 16 MB)

    hipMemsetAsync(d_ws, 0, zero_bytes, stream);

    // ---- fused prep (cast + 3 transposes + w1s + ELL edge build) ----
    prep_k<<<dim3(5296), dim3(256), 0, stream>>>(x, W1, W2, fc1w, a_src1, a_dst1, ei,
                                                 x_bf, Wt1, Wt2, fc1wt, w1sT,
                                                 srcELL, indeg);

    // ---- layer 1 (x-space aggregation; h1 never materialized) ----
    alpha1_k<<<dim3(64), dim3(256), 0, stream>>>(x_bf, w1sT, as1, ad1);
    aggx_k<<<dim3(NN / 4), dim3(256), 0, stream>>>(x_bf, as1, ad1, indeg, srcELL, xagg);
    gemmh_k<<<dim3(32, 4, 8), dim3(256), 0, stream>>>(xagg, Wt1, b1, out1bf);

    // ---- layer 2: gemm2 (split-K=4) with fused ticketed reduce + alpha2 ----
    gemm2f_k<<<dim3(32, 4, 4), dim3(256), 0, stream>>>(
        out1bf, Wt2, part, ticket, a_src2, a_dst2, h2bf, as2, ad2);
    aggregate2_k<<<dim3(NN / 4), dim3(256), 0, stream>>>(
        h2bf, as2, ad2, indeg, srcELL, b2, out2bf);

    // ---- MLP head: fc1 split-K=16 (bf16 partials), then fused reduce+fc2+fc3 ----
    gemm128s_k<<<dim3(4, 4, 16), dim3(256), 0, stream>>>(
        out2bf, fc1wt, part, 512, 512, 4096, 256);
    tail_k<<<dim3(512), dim3(128), 0, stream>>>(
        part, fc1b, fc2w, fc2b, fc3w, fc3b, out);
}

// Round 16
// 205.587 us; speedup vs baseline: 1.4068x; 1.4068x over previous
//
#include <hip/hip_runtime.h>
#include <cstdint>
#include <cstddef>

// Problem constants (fixed by the reference)
#define NN    4096      // nodes
#define E0C   32768     // raw edges
#define ETC   (E0C+NN)  // edges + self loops = 36864
#define HC1   8         // heads layer1
#define CC    512       // channels per head (both layers)
#define F_IN  128
#define NEG_SLOPE_F 0.2f
#define ELLW  64        // ELL width; max in-degree ~Poisson(9) << 64

typedef __bf16 bf16_t;
typedef __bf16 bf16x8 __attribute__((ext_vector_type(8)));
typedef __bf16 bf16x4 __attribute__((ext_vector_type(4)));
typedef __bf16 bf16x2 __attribute__((ext_vector_type(2)));
typedef float  f32x4  __attribute__((ext_vector_type(4)));

// ---------- fused prep: region-dispatched ----------
__device__ __forceinline__ void tcast_body(const float* __restrict__ W, bf16_t* __restrict__ Wt,
                                           int K, int N, int bx, int by)
{
    __shared__ float t[32][33];
    int bn = bx * 32, bk = by * 32;
    int tx = threadIdx.x & 31, ty = threadIdx.x >> 5;
    #pragma unroll
    for (int i = 0; i < 32; i += 8)
        t[ty + i][tx] = W[(size_t)(bk + ty + i) * N + bn + tx];
    __syncthreads();
    #pragma unroll
    for (int i = 0; i < 32; i += 8)
        Wt[(size_t)(bn + ty + i) * K + bk + tx] = (bf16_t)t[tx][ty + i];
}

__global__ __launch_bounds__(256) void prep_k(const float* __restrict__ x,
    const float* __restrict__ W1, const float* __restrict__ W2,
    const float* __restrict__ fc1w, const float* __restrict__ a_src1,
    const float* __restrict__ a_dst1, const int* __restrict__ ei,
    bf16_t* __restrict__ x_bf, bf16_t* __restrict__ Wt1, bf16_t* __restrict__ Wt2,
    bf16_t* __restrict__ fc1wt, bf16_t* __restrict__ w1sT,
    int* __restrict__ srcELL, int* __restrict__ indeg)
{
    const int b = blockIdx.x;
    if (b < 512) {
        int i = (b * 256 + threadIdx.x) * 4;
        float4 v = *(const float4*)&x[i];
        bf16x4 o;
        o[0] = (bf16_t)v.x; o[1] = (bf16_t)v.y; o[2] = (bf16_t)v.z; o[3] = (bf16_t)v.w;
        *(bf16x4*)&x_bf[i] = o;
    } else if (b < 1024) {
        int bl = b - 512;
        tcast_body(W1, Wt1, F_IN, 4096, bl % 128, bl / 128);
    } else if (b < 3072) {
        int bl = b - 1024;
        tcast_body(W2, Wt2, 4096, 512, bl % 16, bl / 16);
    } else if (b < 5120) {
        int bl = b - 3072;
        tcast_body(fc1w, fc1wt, 4096, 512, bl % 16, bl / 16);
    } else if (b < 5152) {
        int bl = b - 5120;                     // 0..31
        int wave = threadIdx.x >> 6, lane = threadIdx.x & 63;
        int k = bl * 4 + wave;                 // 0..127
        int hd = lane >> 3;
        int co = (lane & 7) * 64;
        const float* wrow = W1 + (size_t)k * (HC1 * CC) + hd * CC + co;
        const float* vs = a_src1 + hd * CC + co;
        const float* vd = a_dst1 + hd * CC + co;
        float s = 0.f, d = 0.f;
        #pragma unroll 4
        for (int t = 0; t < 64; ++t) {
            float w = wrow[t];
            s += w * vs[t];
            d += w * vd[t];
        }
        #pragma unroll
        for (int off = 1; off < 8; off <<= 1) {
            s += __shfl_xor(s, off);
            d += __shfl_xor(d, off);
        }
        if ((lane & 7) == 0) {
            w1sT[hd * F_IN + k]       = (bf16_t)s;
            w1sT[(hd + 8) * F_IN + k] = (bf16_t)d;
        }
    } else {
        int e = (b - 5152) * 256 + threadIdx.x;
        if (e < ETC) {
            int s, d;
            if (e < E0C) { s = ei[e]; d = ei[E0C + e]; }
            else         { s = e - E0C; d = s; }
            int pos = atomicAdd(&indeg[d], 1);
            if (pos < ELLW) srcELL[d * ELLW + pos] = s;
        }
    }
}

// ---------- alpha1 via MFMA: [NN x 16] = x_bf[NN x 128] @ w1sT[16 x 128]^T ----------
__global__ __launch_bounds__(256) void alpha1_k(const bf16_t* __restrict__ x_bf,
                                                const bf16_t* __restrict__ w1sT,
                                                float* __restrict__ as1, float* __restrict__ ad1)
{
    const int wave = threadIdx.x >> 6, lane = threadIdx.x & 63;
    const int bm = blockIdx.x * 64 + wave * 16;
    const int lm = lane & 15, quad = lane >> 4;
    f32x4 acc = {};
    #pragma unroll
    for (int k0 = 0; k0 < F_IN; k0 += 32) {
        bf16x8 af = *(const bf16x8*)&x_bf[(size_t)(bm + lm) * F_IN + k0 + quad * 8];
        bf16x8 bf = *(const bf16x8*)&w1sT[lm * F_IN + k0 + quad * 8];
        acc = __builtin_amdgcn_mfma_f32_16x16x32_bf16(af, bf, acc, 0, 0, 0);
    }
    #pragma unroll
    for (int r = 0; r < 4; ++r) {
        int n = bm + quad * 4 + r;
        if (lm < 8) as1[n * HC1 + lm] = acc[r];
        else        ad1[n * HC1 + (lm - 8)] = acc[r];
    }
}

// ---------- layer-1 x-space aggregation: wave per node, all 8 heads ----------
__global__ __launch_bounds__(256) void aggx_k(const bf16_t* __restrict__ x_bf,
    const float* __restrict__ as1, const float* __restrict__ ad1,
    const int* __restrict__ indeg, const int* __restrict__ srcELL,
    bf16_t* __restrict__ xagg)
{
    const int wave = threadIdx.x >> 6, lane = threadIdx.x & 63;
    const int n = blockIdx.x * 4 + wave;
    const int c = lane * 2;
    const int deg = min(indeg[n], ELLW);

    int vsrc = 0;
    float vp[HC1] = {};
    if (lane < deg) {
        vsrc = srcELL[n * ELLW + lane];
        #pragma unroll
        for (int hd = 0; hd < HC1; ++hd) {
            float v = as1[vsrc * HC1 + hd] + ad1[n * HC1 + hd];
            v = (v > 0.f) ? v : NEG_SLOPE_F * v;
            vp[hd] = __expf(v);
        }
    }
    #pragma unroll
    for (int hd = 0; hd < HC1; ++hd) {
        float dsum = vp[hd];
        #pragma unroll
        for (int off = 1; off < 64; off <<= 1)
            dsum += __shfl_xor(dsum, off);
        vp[hd] *= 1.f / dsum;
    }

    float acc[HC1][2] = {};
    int ii = 0;
    for (; ii + 2 <= deg; ii += 2) {
        int s0 = __shfl(vsrc, ii), s1 = __shfl(vsrc, ii + 1);
        bf16x2 r0 = *(const bf16x2*)&x_bf[(size_t)s0 * F_IN + c];
        bf16x2 r1 = *(const bf16x2*)&x_bf[(size_t)s1 * F_IN + c];
        float f00 = (float)r0[0], f01 = (float)r0[1];
        float f10 = (float)r1[0], f11 = (float)r1[1];
        #pragma unroll
        for (int hd = 0; hd < HC1; ++hd) {
            float a0 = __shfl(vp[hd], ii);
            float a1 = __shfl(vp[hd], ii + 1);
            acc[hd][0] += a0 * f00 + a1 * f10;
            acc[hd][1] += a0 * f01 + a1 * f11;
        }
    }
    for (; ii < deg; ++ii) {
        int s = __shfl(vsrc, ii);
        bf16x2 rv = *(const bf16x2*)&x_bf[(size_t)s * F_IN + c];
        float r0 = (float)rv[0], r1 = (float)rv[1];
        #pragma unroll
        for (int hd = 0; hd < HC1; ++hd) {
            float al = __shfl(vp[hd], ii);
            acc[hd][0] += al * r0;
            acc[hd][1] += al * r1;
        }
    }
    #pragma unroll
    for (int hd = 0; hd < HC1; ++hd) {
        bf16x2 o;
        o[0] = (bf16_t)acc[hd][0];
        o[1] = (bf16_t)acc[hd][1];
        *(bf16x2*)&xagg[((size_t)n * HC1 + hd) * F_IN + c] = o;
    }
}

// ---------- per-head batched GEMM: out1[:, hd*512:+512] = relu(xagg[:,hd,:] @ W1h + b1) ----------
__global__ __launch_bounds__(256, 2) void gemmh_k(const bf16_t* __restrict__ xagg,
                                                  const bf16_t* __restrict__ Wt1,
                                                  const float* __restrict__ b1,
                                                  bf16_t* __restrict__ out1)
{
    __shared__ bf16_t As[128 * 32];
    __shared__ bf16_t Bs[128 * 32];
    const int tid = threadIdx.x;
    const int bm = blockIdx.x * 128, bn = blockIdx.y * 128;
    const int hd = blockIdx.z;

    const int wave = tid >> 6, lane = tid & 63;
    const int wm = wave >> 1, wn = wave & 1;
    const int lm = lane & 15, quad = lane >> 4;

    const int sr = tid >> 2;
    const int kg = tid & 3;
    const int swz = ((kg ^ (sr & 3)) * 8);

    const bf16_t* Aptr = xagg + ((size_t)(bm + sr) * HC1 + hd) * F_IN + kg * 8;
    const bf16_t* Bptr = Wt1 + (size_t)(hd * CC + bn + sr) * F_IN + kg * 8;
    const size_t raskip = (size_t)64 * HC1 * F_IN;
    const size_t rbskip = (size_t)64 * F_IN;

    bf16x8 ra0 = *(const bf16x8*)(Aptr);
    bf16x8 ra1 = *(const bf16x8*)(Aptr + raskip);
    bf16x8 rb0 = *(const bf16x8*)(Bptr);
    bf16x8 rb1 = *(const bf16x8*)(Bptr + rbskip);

    f32x4 acc[4][4] = {};

    for (int k0 = 0; k0 < F_IN; k0 += 32) {
        __syncthreads();
        *(bf16x8*)&As[sr * 32 + swz]        = ra0;
        *(bf16x8*)&As[(sr + 64) * 32 + swz] = ra1;
        *(bf16x8*)&Bs[sr * 32 + swz]        = rb0;
        *(bf16x8*)&Bs[(sr + 64) * 32 + swz] = rb1;
        __syncthreads();
        if (k0 + 32 < F_IN) {
            Aptr += 32; Bptr += 32;
            ra0 = *(const bf16x8*)(Aptr);
            ra1 = *(const bf16x8*)(Aptr + raskip);
            rb0 = *(const bf16x8*)(Bptr);
            rb1 = *(const bf16x8*)(Bptr + rbskip);
        }
        const int fswz = ((quad ^ (lm & 3)) * 8);
        bf16x8 af[4], bfr[4];
        #pragma unroll
        for (int i = 0; i < 4; ++i) {
            af[i]  = *(const bf16x8*)&As[(wm * 64 + i * 16 + lm) * 32 + fswz];
            bfr[i] = *(const bf16x8*)&Bs[(wn * 64 + i * 16 + lm) * 32 + fswz];
        }
        #pragma unroll
        for (int mt = 0; mt < 4; ++mt)
            #pragma unroll
            for (int nt = 0; nt < 4; ++nt)
                acc[mt][nt] = __builtin_amdgcn_mfma_f32_16x16x32_bf16(af[mt], bfr[nt], acc[mt][nt], 0, 0, 0);
    }

    #pragma unroll
    for (int nt = 0; nt < 4; ++nt) {
        int gc = bn + wn * 64 + nt * 16 + lm;
        float bv = b1[hd * CC + gc];
        #pragma unroll
        for (int mt = 0; mt < 4; ++mt)
            #pragma unroll
            for (int r = 0; r < 4; ++r) {
                int gr = bm + wm * 64 + mt * 16 + quad * 4 + r;
                out1[(size_t)gr * 4096 + hd * CC + gc] = (bf16_t)fmaxf(acc[mt][nt][r] + bv, 0.f);
            }
    }
}

// ---------- 128x128 MFMA GEMM (NT), XOR-swizzled LDS, split-K, bf16 partials ----------
__global__ __launch_bounds__(256, 2) void gemm128s_k(const bf16_t* __restrict__ A,
                                                     const bf16_t* __restrict__ Bt,
                                                     bf16_t* __restrict__ Cpart,
                                                     int M, int N, int K, int Kc)
{
    __shared__ bf16_t As[128 * 32];
    __shared__ bf16_t Bs[128 * 32];
    const int tid = threadIdx.x;
    const int bm = blockIdx.x * 128, bn = blockIdx.y * 128;
    const int kz = blockIdx.z;
    const int k_beg = kz * Kc;
    const int k_end = k_beg + Kc;

    const int wave = tid >> 6, lane = tid & 63;
    const int wm = wave >> 1, wn = wave & 1;
    const int lm = lane & 15, quad = lane >> 4;

    const int sr = tid >> 2;
    const int kg = tid & 3;
    const int swz = ((kg ^ (sr & 3)) * 8);

    const bf16_t* Aptr = A + (size_t)(bm + sr) * K + k_beg + kg * 8;
    const bf16_t* Bptr = Bt + (size_t)(bn + sr) * K + k_beg + kg * 8;
    const size_t rowskip = (size_t)64 * K;

    bf16x8 ra0 = *(const bf16x8*)(Aptr);
    bf16x8 ra1 = *(const bf16x8*)(Aptr + rowskip);
    bf16x8 rb0 = *(const bf16x8*)(Bptr);
    bf16x8 rb1 = *(const bf16x8*)(Bptr + rowskip);

    f32x4 acc[4][4] = {};

    for (int k0 = k_beg; k0 < k_end; k0 += 32) {
        __syncthreads();
        *(bf16x8*)&As[sr * 32 + swz]        = ra0;
        *(bf16x8*)&As[(sr + 64) * 32 + swz] = ra1;
        *(bf16x8*)&Bs[sr * 32 + swz]        = rb0;
        *(bf16x8*)&Bs[(sr + 64) * 32 + swz] = rb1;
        __syncthreads();
        if (k0 + 32 < k_end) {
            Aptr += 32; Bptr += 32;
            ra0 = *(const bf16x8*)(Aptr);
            ra1 = *(const bf16x8*)(Aptr + rowskip);
            rb0 = *(const bf16x8*)(Bptr);
            rb1 = *(const bf16x8*)(Bptr + rowskip);
        }
        const int fswz = ((quad ^ (lm & 3)) * 8);
        bf16x8 af[4], bfr[4];
        #pragma unroll
        for (int i = 0; i < 4; ++i) {
            af[i]  = *(const bf16x8*)&As[(wm * 64 + i * 16 + lm) * 32 + fswz];
            bfr[i] = *(const bf16x8*)&Bs[(wn * 64 + i * 16 + lm) * 32 + fswz];
        }
        #pragma unroll
        for (int mt = 0; mt < 4; ++mt)
            #pragma unroll
            for (int nt = 0; nt < 4; ++nt)
                acc[mt][nt] = __builtin_amdgcn_mfma_f32_16x16x32_bf16(af[mt], bfr[nt], acc[mt][nt], 0, 0, 0);
    }

    bf16_t* P = Cpart + (size_t)kz * M * N;
    #pragma unroll
    for (int nt = 0; nt < 4; ++nt) {
        int gc = bn + wn * 64 + nt * 16 + lm;
        #pragma unroll
        for (int mt = 0; mt < 4; ++mt)
            #pragma unroll
            for (int r = 0; r < 4; ++r) {
                int gr = bm + wm * 64 + mt * 16 + quad * 4 + r;
                P[(size_t)gr * N + gc] = (bf16_t)acc[mt][nt][r];
            }
    }
}

// ---------- layer-2 reduce: h2 = sum_{z<4} Pz (->bf16), fused as2/ad2 (atomic-free) ----------
// grid 2048, block 256: block covers rows 2b, 2b+1 (threads 0-127 row0, 128-255 row1)
__global__ __launch_bounds__(256) void reduce_h2_k(const bf16_t* __restrict__ P,
    const float* __restrict__ a_s, const float* __restrict__ a_d,
    bf16_t* __restrict__ h2bf, float* __restrict__ as2, float* __restrict__ ad2)
{
    __shared__ float sred[4][2];
    const int t = threadIdx.x;
    const int i = blockIdx.x * 1024 + t * 4;
    f32x4 s = {};
    #pragma unroll
    for (int z = 0; z < 4; ++z) {
        bf16x4 pv = *(const bf16x4*)&P[(size_t)z * NN * CC + i];
        #pragma unroll
        for (int j = 0; j < 4; ++j) s[j] += (float)pv[j];
    }
    bf16x4 o;
    #pragma unroll
    for (int j = 0; j < 4; ++j) o[j] = (bf16_t)s[j];
    *(bf16x4*)&h2bf[i] = o;

    const int c = (t & 127) * 4;
    f32x4 va = *(const f32x4*)&a_s[c];
    f32x4 vd = *(const f32x4*)&a_d[c];
    float ls = s[0]*va[0] + s[1]*va[1] + s[2]*va[2] + s[3]*va[3];
    float ld = s[0]*vd[0] + s[1]*vd[1] + s[2]*vd[2] + s[3]*vd[3];
    #pragma unroll
    for (int off = 32; off > 0; off >>= 1) {
        ls += __shfl_down(ls, off);
        ld += __shfl_down(ld, off);
    }
    const int wave = t >> 6, lane = t & 63;
    if (lane == 0) { sred[wave][0] = ls; sred[wave][1] = ld; }
    __syncthreads();
    if (t == 0) {
        as2[blockIdx.x * 2]     = sred[0][0] + sred[1][0];
        ad2[blockIdx.x * 2]     = sred[0][1] + sred[1][1];
    }
    if (t == 128) {
        as2[blockIdx.x * 2 + 1] = sred[2][0] + sred[3][0];
        ad2[blockIdx.x * 2 + 1] = sred[2][1] + sred[3][1];
    }
}

// ---------- fused tail: f1-row = relu(sum_16 bf16 partials + b); fc2; fc3 ----------
__global__ __launch_bounds__(128) void tail_k(const bf16_t* __restrict__ P,
                                              const float* __restrict__ fc1b,
                                              const float* __restrict__ fc2w,
                                              const float* __restrict__ fc2b,
                                              const float* __restrict__ fc3w,
                                              const float* __restrict__ fc3b,
                                              float* __restrict__ out)
{
    __shared__ float sA[512];
    __shared__ float sF2[128];
    const int m = blockIdx.x, t = threadIdx.x;
    const int MN = 512 * 512;
    #pragma unroll
    for (int i = 0; i < 4; ++i) {
        int c = t + i * 128;
        float v = 0.f;
        #pragma unroll
        for (int z = 0; z < 16; ++z)
            v += (float)P[(size_t)z * MN + (size_t)m * 512 + c];
        sA[c] = fmaxf(v + fc1b[c], 0.f);
    }
    __syncthreads();
    float a0 = 0.f, a1 = 0.f, a2 = 0.f, a3 = 0.f;
    #pragma unroll 4
    for (int k = 0; k < 512; k += 4) {
        a0 += sA[k + 0] * fc2w[(k + 0) * 128 + t];
        a1 += sA[k + 1] * fc2w[(k + 1) * 128 + t];
        a2 += sA[k + 2] * fc2w[(k + 2) * 128 + t];
        a3 += sA[k + 3] * fc2w[(k + 3) * 128 + t];
    }
    sF2[t] = fmaxf((a0 + a1) + (a2 + a3) + fc2b[t], 0.f);
    __syncthreads();
    if (t < 10) {
        float o = fc3b[t];
        #pragma unroll 4
        for (int k = 0; k < 128; ++k)
            o += sF2[k] * fc3w[k * 10 + t];
        out[(size_t)m * 10 + t] = o;
    }
}

// ---------- layer-2 aggregation: one WAVE per node, fused edge-softmax, ELL ----------
__global__ __launch_bounds__(256) void aggregate2_k(const bf16_t* __restrict__ hbuf,
    const float* __restrict__ as, const float* __restrict__ ad,
    const int* __restrict__ indeg, const int* __restrict__ srcELL,
    const float* __restrict__ bias, bf16_t* __restrict__ outb)
{
    const int g = blockIdx.x;
    const int wave = threadIdx.x >> 6, lane = threadIdx.x & 63;
    const int n = g * 4 + wave;
    const int c = lane * 8;

    const int deg = min(indeg[n], ELLW);
    const float adn = ad[n];

    int vsrc = 0; float vp = 0.f;
    if (lane < deg) {
        vsrc = srcELL[n * ELLW + lane];
        float v = as[vsrc] + adn;
        v = (v > 0.f) ? v : NEG_SLOPE_F * v;
        vp = __expf(v);
    }
    float denom = vp;
    #pragma unroll
    for (int off = 1; off < 64; off <<= 1)
        denom += __shfl_xor(denom, off);
    vp *= 1.f / denom;

    float acc[8] = {};
    int ii = 0;
    for (; ii + 4 <= deg; ii += 4) {
        int s0 = __shfl(vsrc, ii),     s1 = __shfl(vsrc, ii + 1);
        int s2 = __shfl(vsrc, ii + 2), s3 = __shfl(vsrc, ii + 3);
        float a0 = __shfl(vp, ii),     a1 = __shfl(vp, ii + 1);
        float a2 = __shfl(vp, ii + 2), a3 = __shfl(vp, ii + 3);
        bf16x8 r0 = *(const bf16x8*)&hbuf[(size_t)s0 * CC + c];
        bf16x8 r1 = *(const bf16x8*)&hbuf[(size_t)s1 * CC + c];
        bf16x8 r2 = *(const bf16x8*)&hbuf[(size_t)s2 * CC + c];
        bf16x8 r3 = *(const bf16x8*)&hbuf[(size_t)s3 * CC + c];
        #pragma unroll
        for (int j = 0; j < 8; ++j) {
            acc[j] += a0 * (float)r0[j];
            acc[j] += a1 * (float)r1[j];
            acc[j] += a2 * (float)r2[j];
            acc[j] += a3 * (float)r3[j];
        }
    }
    for (; ii < deg; ++ii) {
        int s = __shfl(vsrc, ii);
        float al = __shfl(vp, ii);
        bf16x8 rv = *(const bf16x8*)&hbuf[(size_t)s * CC + c];
        #pragma unroll
        for (int j = 0; j < 8; ++j)
            acc[j] += al * (float)rv[j];
    }
    size_t ob = (size_t)n * CC;
    bf16x8 o;
    #pragma unroll
    for (int j = 0; j < 8; ++j)
        o[j] = (bf16_t)fmaxf(acc[j] + bias[c + j], 0.f);
    *(bf16x8*)&outb[ob + c] = o;
}

extern "C" void kernel_launch(void* const* d_in, const int* in_sizes, int n_in,
                              void* d_out, int out_size, void* d_ws, size_t ws_size,
                              hipStream_t stream) {
    const float* x      = (const float*)d_in[0];
    const int*   ei     = (const int*)d_in[1];
    // d_in[2] edge_attr: ignored (GATConv has no edge_dim)
    const float* W1     = (const float*)d_in[3];
    const float* a_src1 = (const float*)d_in[4];
    const float* a_dst1 = (const float*)d_in[5];
    const float* b1     = (const float*)d_in[6];
    const float* W2     = (const float*)d_in[7];
    const float* a_src2 = (const float*)d_in[8];
    const float* a_dst2 = (const float*)d_in[9];
    const float* b2     = (const float*)d_in[10];
    const float* fc1w   = (const float*)d_in[11];
    const float* fc1b   = (const float*)d_in[12];
    const float* fc2w   = (const float*)d_in[13];
    const float* fc2b   = (const float*)d_in[14];
    const float* fc3w   = (const float*)d_in[15];
    const float* fc3b   = (const float*)d_in[16];
    float* out = (float*)d_out;

    // ---- workspace carve-up ----
    char* ws = (char*)d_ws;
    size_t o = 0;
    auto take = [&](size_t bytes) -> char* {
        char* p = ws + o;
        o = (o + bytes + 255) & ~(size_t)255;
        return p;
    };
    // zero-initialized block (indeg only)
    int*    indeg  = (int*)take(NN * 4);
    size_t zero_bytes = o;
    // rest
    float*  as2    = (float*)take(NN * 4);
    float*  ad2    = (float*)take(NN * 4);
    int*    srcELL = (int*)take((size_t)NN * ELLW * 4);
    float*  as1    = (float*)take((size_t)NN * HC1 * 4);
    float*  ad1    = (float*)take((size_t)NN * HC1 * 4);
    bf16_t* w1sT   = (bf16_t*)take((size_t)16 * F_IN * 2);
    bf16_t* x_bf   = (bf16_t*)take((size_t)NN * F_IN * 2);
    bf16_t* xagg   = (bf16_t*)take((size_t)NN * HC1 * F_IN * 2);   // [N][H][128]
    bf16_t* Wt1    = (bf16_t*)take((size_t)F_IN * 4096 * 2);       // [4096][128]
    bf16_t* Wt2    = (bf16_t*)take((size_t)4096 * 512 * 2);        // [512][4096]
    bf16_t* fc1wt  = (bf16_t*)take((size_t)4096 * 512 * 2);        // [512][4096]
    bf16_t* out1bf = (bf16_t*)take((size_t)NN * 4096 * 2);         // GAT1 out (bf16)
    bf16_t* h2bf   = (bf16_t*)take((size_t)NN * 512 * 2);          // GEMM2 out (bf16)
    bf16_t* out2bf = (bf16_t*)take((size_t)NN * 512 * 2);          // GAT2 out (bf16)
    bf16_t* part   = (bf16_t*)take((size_t)4 * NN * 512 * 2);      // split-K partials (bf16, 16 MB)

    hipMemsetAsync(d_ws, 0, zero_bytes, stream);

    // ---- fused prep (cast + 3 transposes + w1s + ELL edge build) ----
    prep_k<<<dim3(5296), dim3(256), 0, stream>>>(x, W1, W2, fc1w, a_src1, a_dst1, ei,
                                                 x_bf, Wt1, Wt2, fc1wt, w1sT,
                                                 srcELL, indeg);

    // ---- layer 1 (x-space aggregation; h1 never materialized) ----
    alpha1_k<<<dim3(64), dim3(256), 0, stream>>>(x_bf, w1sT, as1, ad1);
    aggx_k<<<dim3(NN / 4), dim3(256), 0, stream>>>(x_bf, as1, ad1, indeg, srcELL, xagg);
    gemmh_k<<<dim3(32, 4, 8), dim3(256), 0, stream>>>(xagg, Wt1, b1, out1bf);

    // ---- layer 2: h2 = out1 @ W2 (split-K=4, bf16 partials), fused alpha2 in reduce ----
    gemm128s_k<<<dim3(32, 4, 4), dim3(256), 0, stream>>>(
        out1bf, Wt2, part, 4096, 512, 4096, 1024);
    reduce_h2_k<<<dim3(NN / 2), dim3(256), 0, stream>>>(
        part, a_src2, a_dst2, h2bf, as2, ad2);
    aggregate2_k<<<dim3(NN / 4), dim3(256), 0, stream>>>(
        h2bf, as2, ad2, indeg, srcELL, b2, out2bf);

    // ---- MLP head: fc1 split-K=16 (bf16 partials), then fused reduce+fc2+fc3 ----
    gemm128s_k<<<dim3(4, 4, 16), dim3(256), 0, stream>>>(
        out2bf, fc1wt, part, 512, 512, 4096, 256);
    tail_k<<<dim3(512), dim3(128), 0, stream>>>(
        part, fc1b, fc2w, fc2b, fc3w, fc3b, out);
}